// Round 1
// baseline (659.968 us; speedup 1.0000x reference)
//
#include <hip/hip_runtime.h>
#include <hip/hip_bf16.h>

// Problem: B=16,S=64 -> BS=1024 sequences, L=128 tokens, D=512, F=256 filters
// per conv width Kw in {3,4,5}, V=30000.
// out[bs, c*256 + f] = relu(max_t (conv_c(x)[t,f]) + b_c[f]), fp32.
//
// Strategy: gather+cast embed rows to bf16 x[bs][132][512] (4 zero-pad rows),
// transpose weights to wq[c][f][k][d] bf16, then one implicit-GEMM kernel per
// (bs, conv-halftile) block: 128x128 tile, BK=64, 16x16x32 bf16 MFMA,
// global_load_lds width-16 staging (m97 structure), fused max/bias/relu.

typedef __bf16 bf16x8 __attribute__((ext_vector_type(8)));
typedef float f32x4 __attribute__((ext_vector_type(4)));

#define XROWS 132                   // 128 real + 4 zero pad (K=5 window)
#define XELEMS ((size_t)1024 * XROWS * 512)
#define WQ_ELEMS 1572864            // 256*(1536+2048+2560)

__device__ __forceinline__ void async16(const void* g, void* l) {
    __builtin_amdgcn_global_load_lds(
        (const __attribute__((address_space(1))) void*)g,
        (__attribute__((address_space(3))) void*)l, 16, 0, 0);
}

// ---------------- pack_x: x[bs][t][d] = bf16(embed[text[bs,t], d]) ----------
// 256 threads/block, 4 rows/block (64 threads x 8 elems = 512/row).
__global__ void pack_x_kernel(const int* __restrict__ text,
                              const float* __restrict__ embed,
                              __bf16* __restrict__ x) {
    const int tid  = threadIdx.x;
    const int rr   = blockIdx.x * 4 + (tid >> 6);   // global row 0..135167
    const int lane = tid & 63;
    const int bs   = rr / XROWS;
    const int t    = rr - bs * XROWS;
    __bf16* dst = x + (size_t)rr * 512 + lane * 8;
    bf16x8 o = {};
    if (t < 128) {
        const int token = text[bs * 128 + t];
        const float* src = embed + (size_t)token * 512 + lane * 8;
        const float4 v0 = *(const float4*)(src);
        const float4 v1 = *(const float4*)(src + 4);
        o[0] = (__bf16)v0.x; o[1] = (__bf16)v0.y;
        o[2] = (__bf16)v0.z; o[3] = (__bf16)v0.w;
        o[4] = (__bf16)v1.x; o[5] = (__bf16)v1.y;
        o[6] = (__bf16)v1.z; o[7] = (__bf16)v1.w;
    }
    *(bf16x8*)dst = o;
}

// ---------------- pack_w: wq[c][f][k][d] = bf16(w_c[f][d][k]) ---------------
__global__ void pack_w_kernel(const float* __restrict__ w3,
                              const float* __restrict__ w4,
                              const float* __restrict__ w5,
                              __bf16* __restrict__ wq) {
    const int e = blockIdx.x * 256 + threadIdx.x;   // 0..1572863
    int rel, Kw; const float* w;
    if (e < 393216)      { rel = e;          Kw = 3; w = w3; }
    else if (e < 917504) { rel = e - 393216; Kw = 4; w = w4; }
    else                 { rel = e - 917504; Kw = 5; w = w5; }
    const int fk = rel >> 9;          // f*Kw + k
    const int d  = rel & 511;
    const int f  = fk / Kw;
    const int k  = fk - f * Kw;
    wq[e] = (__bf16)w[((size_t)f * 512 + d) * Kw + k];
}

// ---------------- gemm + max-over-time + bias + relu ------------------------
// grid = (1024, 6): blockIdx.x = bs, blockIdx.y = conv*2 + halftile.
// Tile: M=128 (t, Tvalid=126-c real), N=128 (filters), BK=64.
__global__ __launch_bounds__(256) void gemm_max_kernel(
        const __bf16* __restrict__ x,
        const __bf16* __restrict__ wq,
        const float* __restrict__ b3,
        const float* __restrict__ b4,
        const float* __restrict__ b5,
        float* __restrict__ out) {
    __shared__ __bf16 As[128 * 64];
    __shared__ __bf16 Bs[128 * 64];

    const int tid  = threadIdx.x;
    const int wave = tid >> 6;
    const int lane = tid & 63;
    const int bs   = blockIdx.x;
    const int c    = blockIdx.y >> 1;     // conv id 0..2 (Kw = 3+c)
    const int nh   = blockIdx.y & 1;      // filter half-tile
    const int Kd   = (3 + c) << 9;        // 1536 / 2048 / 2560
    const int niter = Kd >> 6;            // 24 / 32 / 40

    const int wbase = (c == 0) ? 0 : (c == 1) ? 393216 : 917504;
    const __bf16* xb = x + (size_t)bs * (XROWS * 512);
    const __bf16* wb = wq + wbase + (size_t)nh * 128 * Kd;

    // staging: wave handles rows [wave*32, wave*32+32), 8 rows per instr
    const int arow = wave * 32 + (lane >> 3);
    const int acol = (lane & 7) * 8;
    __bf16* lA = &As[(wave * 32) * 64];
    __bf16* lB = &Bs[(wave * 32) * 64];

    // compute: 2x2 wave grid, each wave 64x64 via 4x4 of 16x16x32
    const int wm = wave & 1, wn = wave >> 1;
    const int lm = lane & 15, lk = lane >> 4;

    f32x4 acc[4][4];
#pragma unroll
    for (int i = 0; i < 4; ++i)
#pragma unroll
        for (int j = 0; j < 4; ++j) acc[i][j] = (f32x4){0.f, 0.f, 0.f, 0.f};

    for (int it = 0; it < niter; ++it) {
        const int kk0 = it << 6;
        const int kt  = kk0 >> 9;     // tap index (A row shift)
        const int dB  = kk0 & 511;    // d base within tap
        const __bf16* ga = xb + (size_t)(kt + arow) * 512 + dB + acol;
        async16(ga,            lA);
        async16(ga +  8 * 512, lA +  8 * 64);
        async16(ga + 16 * 512, lA + 16 * 64);
        async16(ga + 24 * 512, lA + 24 * 64);
        const __bf16* gb = wb + (size_t)arow * Kd + kk0 + acol;
        async16(gb,            lB);
        async16(gb +  8 * Kd,  lB +  8 * 64);
        async16(gb + 16 * Kd,  lB + 16 * 64);
        async16(gb + 24 * Kd,  lB + 24 * 64);
        __syncthreads();
#pragma unroll
        for (int ks = 0; ks < 2; ++ks) {
            bf16x8 a[4], b[4];
#pragma unroll
            for (int mt = 0; mt < 4; ++mt)
                a[mt] = *(const bf16x8*)&As[(wm * 64 + mt * 16 + lm) * 64 + ks * 32 + lk * 8];
#pragma unroll
            for (int nt = 0; nt < 4; ++nt)
                b[nt] = *(const bf16x8*)&Bs[(wn * 64 + nt * 16 + lm) * 64 + ks * 32 + lk * 8];
#pragma unroll
            for (int mt = 0; mt < 4; ++mt)
#pragma unroll
                for (int nt = 0; nt < 4; ++nt)
                    acc[mt][nt] = __builtin_amdgcn_mfma_f32_16x16x32_bf16(
                        a[mt], b[nt], acc[mt][nt], 0, 0, 0);
        }
        __syncthreads();
    }

    // epilogue: max over valid t (m), then cross-lane, cross-wave reduce
    const int Tv = 126 - c;           // 126/125/124 valid positions
    float cmax[4];
#pragma unroll
    for (int nt = 0; nt < 4; ++nt) {
        float mx = -3.0e38f;
#pragma unroll
        for (int mt = 0; mt < 4; ++mt) {
            const int mb = wm * 64 + mt * 16 + lk * 4;
#pragma unroll
            for (int r = 0; r < 4; ++r) {
                const float v = acc[mt][nt][r];
                if (mb + r < Tv) mx = fmaxf(mx, v);
            }
        }
        mx = fmaxf(mx, __shfl_xor(mx, 16, 64));
        mx = fmaxf(mx, __shfl_xor(mx, 32, 64));
        cmax[nt] = mx;
    }
    float* red = (float*)As;          // [2][128] partials (As dead now)
    if (lk == 0) {
#pragma unroll
        for (int nt = 0; nt < 4; ++nt)
            red[wm * 128 + wn * 64 + nt * 16 + lm] = cmax[nt];
    }
    __syncthreads();
    if (tid < 128) {
        const float* bias = (c == 0) ? b3 : (c == 1) ? b4 : b5;
        const int fg = nh * 128 + tid;                 // filter within conv
        float v = fmaxf(red[tid], red[128 + tid]) + bias[fg];
        out[(size_t)bs * 768 + c * 256 + fg] = fmaxf(v, 0.f);
    }
}

extern "C" void kernel_launch(void* const* d_in, const int* in_sizes, int n_in,
                              void* d_out, int out_size, void* d_ws, size_t ws_size,
                              hipStream_t stream) {
    const int*   text  = (const int*)d_in[0];
    const float* embed = (const float*)d_in[1];
    const float* w3    = (const float*)d_in[2];
    const float* b3    = (const float*)d_in[3];
    const float* w4    = (const float*)d_in[4];
    const float* b4    = (const float*)d_in[5];
    const float* w5    = (const float*)d_in[6];
    const float* b5    = (const float*)d_in[7];
    float* out = (float*)d_out;

    __bf16* x  = (__bf16*)d_ws;                 // 1024*132*512 bf16 = 138.4 MB
    __bf16* wq = x + XELEMS;                    // 1572864 bf16 = 3.1 MB

    pack_x_kernel<<<1024 * XROWS / 4, 256, 0, stream>>>(text, embed, x);
    pack_w_kernel<<<WQ_ELEMS / 256, 256, 0, stream>>>(w3, w4, w5, wq);
    dim3 grid(1024, 6);
    gemm_max_kernel<<<grid, 256, 0, stream>>>(x, wq, b3, b4, b5, out);
}

// Round 2
// 602.976 us; speedup vs baseline: 1.0945x; 1.0945x over previous
//
#include <hip/hip_runtime.h>
#include <hip/hip_bf16.h>

// Problem: B=16,S=64 -> BS=1024 sequences, L=128 tokens, D=512, F=256 filters
// per conv width Kw in {3,4,5}, V=30000.
// out[bs, c*256 + f] = relu(max_t (conv_c(x)[t,f]) + b_c[f]), fp32.
//
// R2: XOR-swizzled LDS layout to kill the 1.5e8 LDS bank conflicts seen in R1
// (row stride 128 B == 32 banks meant each b128 fragment read hit only 4 of 8
// 16B bank-groups). Data block cb of row r stored at block cb^(r&7); the
// global_load_lds source column is swizzled per-lane (dst is fixed lane*16).

typedef __bf16 bf16x8 __attribute__((ext_vector_type(8)));
typedef float f32x4 __attribute__((ext_vector_type(4)));

#define XROWS 132                   // 128 real + 4 zero pad (K=5 window)
#define XELEMS ((size_t)1024 * XROWS * 512)
#define WQ_ELEMS 1572864            // 256*(1536+2048+2560)

__device__ __forceinline__ void async16(const void* g, void* l) {
    __builtin_amdgcn_global_load_lds(
        (const __attribute__((address_space(1))) void*)g,
        (__attribute__((address_space(3))) void*)l, 16, 0, 0);
}

// ---------------- pack_x: x[bs][t][d] = bf16(embed[text[bs,t], d]) ----------
// 256 threads/block, 4 rows/block (64 threads x 8 elems = 512/row).
__global__ void pack_x_kernel(const int* __restrict__ text,
                              const float* __restrict__ embed,
                              __bf16* __restrict__ x) {
    const int tid  = threadIdx.x;
    const int rr   = blockIdx.x * 4 + (tid >> 6);   // global row 0..135167
    const int lane = tid & 63;
    const int bs   = rr / XROWS;
    const int t    = rr - bs * XROWS;
    __bf16* dst = x + (size_t)rr * 512 + lane * 8;
    bf16x8 o = {};
    if (t < 128) {
        const int token = text[bs * 128 + t];
        const float* src = embed + (size_t)token * 512 + lane * 8;
        const float4 v0 = *(const float4*)(src);
        const float4 v1 = *(const float4*)(src + 4);
        o[0] = (__bf16)v0.x; o[1] = (__bf16)v0.y;
        o[2] = (__bf16)v0.z; o[3] = (__bf16)v0.w;
        o[4] = (__bf16)v1.x; o[5] = (__bf16)v1.y;
        o[6] = (__bf16)v1.z; o[7] = (__bf16)v1.w;
    }
    *(bf16x8*)dst = o;
}

// ---------------- pack_w: wq[c][f][k][d] = bf16(w_c[f][d][k]) ---------------
__global__ void pack_w_kernel(const float* __restrict__ w3,
                              const float* __restrict__ w4,
                              const float* __restrict__ w5,
                              __bf16* __restrict__ wq) {
    const int e = blockIdx.x * 256 + threadIdx.x;   // 0..1572863
    int rel, Kw; const float* w;
    if (e < 393216)      { rel = e;          Kw = 3; w = w3; }
    else if (e < 917504) { rel = e - 393216; Kw = 4; w = w4; }
    else                 { rel = e - 917504; Kw = 5; w = w5; }
    const int fk = rel >> 9;          // f*Kw + k
    const int d  = rel & 511;
    const int f  = fk / Kw;
    const int k  = fk - f * Kw;
    wq[e] = (__bf16)w[((size_t)f * 512 + d) * Kw + k];
}

// ---------------- gemm + max-over-time + bias + relu ------------------------
// grid = (1024, 6): blockIdx.x = bs, blockIdx.y = conv*2 + halftile.
// Tile: M=128 (t, Tvalid=126-c real), N=128 (filters), BK=64.
// LDS swizzle: data block cb (16B units) of row r lives at block cb^(r&7).
__global__ __launch_bounds__(256) void gemm_max_kernel(
        const __bf16* __restrict__ x,
        const __bf16* __restrict__ wq,
        const float* __restrict__ b3,
        const float* __restrict__ b4,
        const float* __restrict__ b5,
        float* __restrict__ out) {
    __shared__ __bf16 As[128 * 64];
    __shared__ __bf16 Bs[128 * 64];

    const int tid  = threadIdx.x;
    const int wave = tid >> 6;
    const int lane = tid & 63;
    const int bs   = blockIdx.x;
    const int c    = blockIdx.y >> 1;     // conv id 0..2 (Kw = 3+c)
    const int nh   = blockIdx.y & 1;      // filter half-tile
    const int Kd   = (3 + c) << 9;        // 1536 / 2048 / 2560
    const int niter = Kd >> 6;            // 24 / 32 / 40

    const int wbase = (c == 0) ? 0 : (c == 1) ? 393216 : 917504;
    const __bf16* xb = x + (size_t)bs * (XROWS * 512);
    const __bf16* wb = wq + wbase + (size_t)nh * 128 * Kd;

    // staging: wave handles rows [wave*32, wave*32+32), 8 rows per instr.
    // Source column block is XOR-swizzled: lane stores block (lane&7), which
    // must hold data block (lane&7)^(row&7); row&7 == (lane>>3)&7 (rows step
    // by 8 across the 4 async16 calls, so the swizzle is lane-only).
    const int arow = wave * 32 + (lane >> 3);
    const int asw  = ((lane & 7) ^ ((lane >> 3) & 7)) * 8;  // bf16 units
    __bf16* lA = &As[(wave * 32) * 64];
    __bf16* lB = &Bs[(wave * 32) * 64];

    // compute: 2x2 wave grid, each wave 64x64 via 4x4 of 16x16x32
    const int wm = wave & 1, wn = wave >> 1;
    const int lm = lane & 15, lk = lane >> 4;

    f32x4 acc[4][4];
#pragma unroll
    for (int i = 0; i < 4; ++i)
#pragma unroll
        for (int j = 0; j < 4; ++j) acc[i][j] = (f32x4){0.f, 0.f, 0.f, 0.f};

    for (int it = 0; it < niter; ++it) {
        const int kk0 = it << 6;
        const int kt  = kk0 >> 9;     // tap index (A row shift)
        const int dB  = kk0 & 511;    // d base within tap
        const __bf16* ga = xb + (size_t)(kt + arow) * 512 + dB + asw;
        async16(ga,            lA);
        async16(ga +  8 * 512, lA +  8 * 64);
        async16(ga + 16 * 512, lA + 16 * 64);
        async16(ga + 24 * 512, lA + 24 * 64);
        const __bf16* gb = wb + (size_t)arow * Kd + kk0 + asw;
        async16(gb,            lB);
        async16(gb +  8 * Kd,  lB +  8 * 64);
        async16(gb + 16 * Kd,  lB + 16 * 64);
        async16(gb + 24 * Kd,  lB + 24 * 64);
        __syncthreads();
#pragma unroll
        for (int ks = 0; ks < 2; ++ks) {
            bf16x8 a[4], b[4];
#pragma unroll
            for (int mt = 0; mt < 4; ++mt)
                a[mt] = *(const bf16x8*)
                    &As[(wm * 64 + mt * 16 + lm) * 64 +
                        (((ks * 4 + lk) ^ (lm & 7)) * 8)];
#pragma unroll
            for (int nt = 0; nt < 4; ++nt)
                b[nt] = *(const bf16x8*)
                    &Bs[(wn * 64 + nt * 16 + lm) * 64 +
                        (((ks * 4 + lk) ^ (lm & 7)) * 8)];
#pragma unroll
            for (int mt = 0; mt < 4; ++mt)
#pragma unroll
                for (int nt = 0; nt < 4; ++nt)
                    acc[mt][nt] = __builtin_amdgcn_mfma_f32_16x16x32_bf16(
                        a[mt], b[nt], acc[mt][nt], 0, 0, 0);
        }
        __syncthreads();
    }

    // epilogue: max over valid t (m), then cross-lane, cross-wave reduce
    const int Tv = 126 - c;           // 126/125/124 valid positions
    float cmax[4];
#pragma unroll
    for (int nt = 0; nt < 4; ++nt) {
        float mx = -3.0e38f;
#pragma unroll
        for (int mt = 0; mt < 4; ++mt) {
            const int mb = wm * 64 + mt * 16 + lk * 4;
#pragma unroll
            for (int r = 0; r < 4; ++r) {
                const float v = acc[mt][nt][r];
                if (mb + r < Tv) mx = fmaxf(mx, v);
            }
        }
        mx = fmaxf(mx, __shfl_xor(mx, 16, 64));
        mx = fmaxf(mx, __shfl_xor(mx, 32, 64));
        cmax[nt] = mx;
    }
    float* red = (float*)As;          // [2][128] partials (As dead now)
    if (lk == 0) {
#pragma unroll
        for (int nt = 0; nt < 4; ++nt)
            red[wm * 128 + wn * 64 + nt * 16 + lm] = cmax[nt];
    }
    __syncthreads();
    if (tid < 128) {
        const float* bias = (c == 0) ? b3 : (c == 1) ? b4 : b5;
        const int fg = nh * 128 + tid;                 // filter within conv
        float v = fmaxf(red[tid], red[128 + tid]) + bias[fg];
        out[(size_t)bs * 768 + c * 256 + fg] = fmaxf(v, 0.f);
    }
}

extern "C" void kernel_launch(void* const* d_in, const int* in_sizes, int n_in,
                              void* d_out, int out_size, void* d_ws, size_t ws_size,
                              hipStream_t stream) {
    const int*   text  = (const int*)d_in[0];
    const float* embed = (const float*)d_in[1];
    const float* w3    = (const float*)d_in[2];
    const float* b3    = (const float*)d_in[3];
    const float* w4    = (const float*)d_in[4];
    const float* b4    = (const float*)d_in[5];
    const float* w5    = (const float*)d_in[6];
    const float* b5    = (const float*)d_in[7];
    float* out = (float*)d_out;

    __bf16* x  = (__bf16*)d_ws;                 // 1024*132*512 bf16 = 138.4 MB
    __bf16* wq = x + XELEMS;                    // 1572864 bf16 = 3.1 MB

    pack_x_kernel<<<1024 * XROWS / 4, 256, 0, stream>>>(text, embed, x);
    pack_w_kernel<<<WQ_ELEMS / 256, 256, 0, stream>>>(w3, w4, w5, wq);
    dim3 grid(1024, 6);
    gemm_max_kernel<<<grid, 256, 0, stream>>>(x, wq, b3, b4, b5, out);
}

// Round 3
// 582.520 us; speedup vs baseline: 1.1330x; 1.0351x over previous
//
#include <hip/hip_runtime.h>
#include <hip/hip_bf16.h>

// Problem: B=16,S=64 -> BS=1024 sequences, L=128 tokens, D=512, F=256 filters
// per conv width Kw in {3,4,5}, V=30000.
// out[bs, c*256 + f] = relu(max_t (conv_c(x)[t,f]) + b_c[f]), fp32.
//
// R2: XOR-swizzled LDS layout -> bank conflicts 1.5e8 -> 0 (550->461 us).
// R3: XCD-aware 1D grid remap: the 6 blocks sharing one bs's x-slab (3 convs
//     x 2 half-tiles) are made consecutive on one XCD (block->XCD is ~lin%8),
//     so the 135 KB slab + 3 MB weights stay L2-resident. R2 showed 1.65 GB
//     HBM fetch vs 141 MB unique (12x over-fetch). Also strength-reduced
//     staging addresses (A and B both advance exactly 128 B/iter).

typedef __bf16 bf16x8 __attribute__((ext_vector_type(8)));
typedef float f32x4 __attribute__((ext_vector_type(4)));

#define XROWS 132                   // 128 real + 4 zero pad (K=5 window)
#define XELEMS ((size_t)1024 * XROWS * 512)
#define WQ_ELEMS 1572864            // 256*(1536+2048+2560)

__device__ __forceinline__ void async16(const void* g, void* l) {
    __builtin_amdgcn_global_load_lds(
        (const __attribute__((address_space(1))) void*)g,
        (__attribute__((address_space(3))) void*)l, 16, 0, 0);
}

// ---------------- pack_x: x[bs][t][d] = bf16(embed[text[bs,t], d]) ----------
__global__ void pack_x_kernel(const int* __restrict__ text,
                              const float* __restrict__ embed,
                              __bf16* __restrict__ x) {
    const int tid  = threadIdx.x;
    const int rr   = blockIdx.x * 4 + (tid >> 6);   // global row 0..135167
    const int lane = tid & 63;
    const int bs   = rr / XROWS;
    const int t    = rr - bs * XROWS;
    __bf16* dst = x + (size_t)rr * 512 + lane * 8;
    bf16x8 o = {};
    if (t < 128) {
        const int token = text[bs * 128 + t];
        const float* src = embed + (size_t)token * 512 + lane * 8;
        const float4 v0 = *(const float4*)(src);
        const float4 v1 = *(const float4*)(src + 4);
        o[0] = (__bf16)v0.x; o[1] = (__bf16)v0.y;
        o[2] = (__bf16)v0.z; o[3] = (__bf16)v0.w;
        o[4] = (__bf16)v1.x; o[5] = (__bf16)v1.y;
        o[6] = (__bf16)v1.z; o[7] = (__bf16)v1.w;
    }
    *(bf16x8*)dst = o;
}

// ---------------- pack_w: wq[c][f][k][d] = bf16(w_c[f][d][k]) ---------------
__global__ void pack_w_kernel(const float* __restrict__ w3,
                              const float* __restrict__ w4,
                              const float* __restrict__ w5,
                              __bf16* __restrict__ wq) {
    const int e = blockIdx.x * 256 + threadIdx.x;   // 0..1572863
    int rel, Kw; const float* w;
    if (e < 393216)      { rel = e;          Kw = 3; w = w3; }
    else if (e < 917504) { rel = e - 393216; Kw = 4; w = w4; }
    else                 { rel = e - 917504; Kw = 5; w = w5; }
    const int fk = rel >> 9;          // f*Kw + k
    const int d  = rel & 511;
    const int f  = fk / Kw;
    const int k  = fk - f * Kw;
    wq[e] = (__bf16)w[((size_t)f * 512 + d) * Kw + k];
}

// ---------------- gemm + max-over-time + bias + relu ------------------------
// 1D grid 6144. XCD-aware decode: xcd = lin&7, per-XCD index = lin>>3;
// bs = (idx/6)*8 + xcd, cy = idx%6 = conv*2 + halftile. The 6 blocks of one
// bs are consecutive on one XCD -> x slab + weights stay in that XCD's L2.
// Tile: M=128 (t, Tvalid=126-c real), N=128 (filters), BK=64.
// LDS swizzle: data block cb (16B units) of row r lives at block cb^(r&7).
__global__ __launch_bounds__(256) void gemm_max_kernel(
        const __bf16* __restrict__ x,
        const __bf16* __restrict__ wq,
        const float* __restrict__ b3,
        const float* __restrict__ b4,
        const float* __restrict__ b5,
        float* __restrict__ out) {
    __shared__ __bf16 As[128 * 64];
    __shared__ __bf16 Bs[128 * 64];

    const int tid  = threadIdx.x;
    const int wave = tid >> 6;
    const int lane = tid & 63;

    const int lin  = blockIdx.x;
    const int xcd  = lin & 7;
    const int idx  = lin >> 3;            // per-XCD dispatch index
    const int bsh  = idx / 6;
    const int cy   = idx - bsh * 6;       // 0..5
    const int bs   = bsh * 8 + xcd;       // 0..1023
    const int c    = cy >> 1;             // conv id 0..2 (Kw = 3+c)
    const int nh   = cy & 1;              // filter half-tile
    const int Kd   = (3 + c) << 9;        // 1536 / 2048 / 2560
    const int niter = Kd >> 6;            // 24 / 32 / 40

    const int wbase = (c == 0) ? 0 : (c == 1) ? 393216 : 917504;
    const __bf16* xb = x + (size_t)bs * (XROWS * 512);
    const __bf16* wb = wq + wbase + (size_t)nh * 128 * Kd;

    // staging: wave handles rows [wave*32, wave*32+32), 8 rows per instr.
    // Source column block is XOR-swizzled (dst is fixed lane*16): lane's
    // block (lane&7) holds data block (lane&7)^(row&7), row&7 == (lane>>3)&7.
    const int arow = wave * 32 + (lane >> 3);
    const int asw  = ((lane & 7) ^ ((lane >> 3) & 7)) * 8;  // bf16 units
    __bf16* lA = &As[(wave * 32) * 64];
    __bf16* lB = &Bs[(wave * 32) * 64];

    // A offset: (kt+arow)*512 + dB + asw = arow*512 + it*64 + asw.
    const __bf16* ga = xb + (size_t)arow * 512 + asw;
    const __bf16* gb = wb + (size_t)arow * Kd + asw;

    // compute: 2x2 wave grid, each wave 64x64 via 4x4 of 16x16x32
    const int wm = wave & 1, wn = wave >> 1;
    const int lm = lane & 15, lk = lane >> 4;

    f32x4 acc[4][4];
#pragma unroll
    for (int i = 0; i < 4; ++i)
#pragma unroll
        for (int j = 0; j < 4; ++j) acc[i][j] = (f32x4){0.f, 0.f, 0.f, 0.f};

    for (int it = 0; it < niter; ++it) {
        async16(ga,            lA);
        async16(ga +  8 * 512, lA +  8 * 64);
        async16(ga + 16 * 512, lA + 16 * 64);
        async16(ga + 24 * 512, lA + 24 * 64);
        async16(gb,            lB);
        async16(gb +  8 * Kd,  lB +  8 * 64);
        async16(gb + 16 * Kd,  lB + 16 * 64);
        async16(gb + 24 * Kd,  lB + 24 * 64);
        ga += 64;
        gb += 64;
        __syncthreads();
#pragma unroll
        for (int ks = 0; ks < 2; ++ks) {
            bf16x8 a[4], b[4];
#pragma unroll
            for (int mt = 0; mt < 4; ++mt)
                a[mt] = *(const bf16x8*)
                    &As[(wm * 64 + mt * 16 + lm) * 64 +
                        (((ks * 4 + lk) ^ (lm & 7)) * 8)];
#pragma unroll
            for (int nt = 0; nt < 4; ++nt)
                b[nt] = *(const bf16x8*)
                    &Bs[(wn * 64 + nt * 16 + lm) * 64 +
                        (((ks * 4 + lk) ^ (lm & 7)) * 8)];
#pragma unroll
            for (int mt = 0; mt < 4; ++mt)
#pragma unroll
                for (int nt = 0; nt < 4; ++nt)
                    acc[mt][nt] = __builtin_amdgcn_mfma_f32_16x16x32_bf16(
                        a[mt], b[nt], acc[mt][nt], 0, 0, 0);
        }
        __syncthreads();
    }

    // epilogue: max over valid t (m), then cross-lane, cross-wave reduce
    const int Tv = 126 - c;           // 126/125/124 valid positions
    float cmax[4];
#pragma unroll
    for (int nt = 0; nt < 4; ++nt) {
        float mx = -3.0e38f;
#pragma unroll
        for (int mt = 0; mt < 4; ++mt) {
            const int mb = wm * 64 + mt * 16 + lk * 4;
#pragma unroll
            for (int r = 0; r < 4; ++r) {
                const float v = acc[mt][nt][r];
                if (mb + r < Tv) mx = fmaxf(mx, v);
            }
        }
        mx = fmaxf(mx, __shfl_xor(mx, 16, 64));
        mx = fmaxf(mx, __shfl_xor(mx, 32, 64));
        cmax[nt] = mx;
    }
    float* red = (float*)As;          // [2][128] partials (As dead now)
    if (lk == 0) {
#pragma unroll
        for (int nt = 0; nt < 4; ++nt)
            red[wm * 128 + wn * 64 + nt * 16 + lm] = cmax[nt];
    }
    __syncthreads();
    if (tid < 128) {
        const float* bias = (c == 0) ? b3 : (c == 1) ? b4 : b5;
        const int fg = nh * 128 + tid;                 // filter within conv
        float v = fmaxf(red[tid], red[128 + tid]) + bias[fg];
        out[(size_t)bs * 768 + c * 256 + fg] = fmaxf(v, 0.f);
    }
}

extern "C" void kernel_launch(void* const* d_in, const int* in_sizes, int n_in,
                              void* d_out, int out_size, void* d_ws, size_t ws_size,
                              hipStream_t stream) {
    const int*   text  = (const int*)d_in[0];
    const float* embed = (const float*)d_in[1];
    const float* w3    = (const float*)d_in[2];
    const float* b3    = (const float*)d_in[3];
    const float* w4    = (const float*)d_in[4];
    const float* b4    = (const float*)d_in[5];
    const float* w5    = (const float*)d_in[6];
    const float* b5    = (const float*)d_in[7];
    float* out = (float*)d_out;

    __bf16* x  = (__bf16*)d_ws;                 // 1024*132*512 bf16 = 138.4 MB
    __bf16* wq = x + XELEMS;                    // 1572864 bf16 = 3.1 MB

    pack_x_kernel<<<1024 * XROWS / 4, 256, 0, stream>>>(text, embed, x);
    pack_w_kernel<<<WQ_ELEMS / 256, 256, 0, stream>>>(w3, w4, w5, wq);
    gemm_max_kernel<<<6144, 256, 0, stream>>>(x, wq, b3, b4, b5, out);
}